// Round 13
// baseline (130.178 us; speedup 1.0000x reference)
//
#include <hip/hip_runtime.h>
#include <math.h>

#define NPTS 4096

typedef __attribute__((ext_vector_type(8))) short bf16x8;
typedef __attribute__((ext_vector_type(16))) float f32x16;

// liveness pin: forbid rematerialization / load sinking (round-5 lesson)
#define KEEP(x) asm volatile("" : "+v"(x))

__device__ __forceinline__ f32x16 zero16() {
  f32x16 z;
#pragma unroll
  for (int i = 0; i < 16; ++i) z[i] = 0.f;
  return z;
}

// monotonic sortable key (ascending with float value) with 12-bit m index
// embedded in the low mantissa bits (clearing them perturbs the compared
// value by ~2^-12 relative -- far below the bf16 noise already tolerated).
__device__ __forceinline__ unsigned packkey(float x, int m) {
  unsigned u = __float_as_uint(x);
  unsigned key = u ^ ((unsigned)((int)u >> 31) | 0x80000000u);
  return (key & 0xFFFFF000u) | (unsigned)m;
}

// inverse of packkey's monotonic map (low bits cleared -> slightly LOW
// threshold = conservative filter)
__device__ __forceinline__ float unpackkey(unsigned key) {
  const unsigned m1 = (unsigned)((int)key >> 31);   // 0 if top bit 0
  return __uint_as_float(key ^ ((~m1) | 0x80000000u));
}

// cascade insert into sorted-descending 7-array: 7 umax + 7 umin, no branches
__device__ __forceinline__ void cas7(unsigned v, unsigned* s) {
#pragma unroll
  for (int t = 0; t < 7; ++t) {
    const unsigned hi = s[t] >= v ? s[t] : v;
    const unsigned lo = s[t] >= v ? v : s[t];
    s[t] = hi;
    v = lo;
  }
}

// sentinel key: unpacks to -3.4e38 (finite!), NOT -NaN (key 0 would unpack
// to -NaN and the epilogue filter would reject everything forever)
#define KSENT 0x00800000u

__device__ __forceinline__ unsigned bf16pack(float a, float b) {
  unsigned ua = __float_as_uint(a); ua = (ua + 0x7FFFu + ((ua >> 16) & 1u)) >> 16;
  unsigned ub = __float_as_uint(b); ub = (ub + 0x7FFFu + ((ub >> 16) & 1u)) >> 16;
  return ua | (ub << 16);
}

// ---------------------------------------------------------------------------
// K1a: normalize features -> fragment-major bf16 Fsw[b][mt][kc(24)][lane(64)][8]
// ---------------------------------------------------------------------------
__global__ __launch_bounds__(64) void norm_f(const float* __restrict__ feats,
                                             unsigned short* __restrict__ Fsw) {
  const int row = blockIdx.x;            // 0 .. 8191
  const int lane = threadIdx.x;
  const int b = row >> 12, mt = (row >> 5) & 127, rl = row & 31;

  const float* f = feats + (size_t)row * 384;
  float v[8];
  float ss = 0.f;
  if (lane < 48) {
    float4 p0 = *(const float4*)(f + lane * 8);
    float4 p1 = *(const float4*)(f + lane * 8 + 4);
    v[0] = p0.x; v[1] = p0.y; v[2] = p0.z; v[3] = p0.w;
    v[4] = p1.x; v[5] = p1.y; v[6] = p1.z; v[7] = p1.w;
#pragma unroll
    for (int e = 0; e < 8; ++e) ss = fmaf(v[e], v[e], ss);
  }
#pragma unroll
  for (int m = 1; m <= 32; m <<= 1) ss += __shfl_xor(ss, m, 64);
  const float inv = rsqrtf(ss + 1e-8f);
  if (lane < 48) {
    uint4 o;
    o.x = bf16pack(v[0] * inv, v[1] * inv);
    o.y = bf16pack(v[2] * inv, v[3] * inv);
    o.z = bf16pack(v[4] * inv, v[5] * inv);
    o.w = bf16pack(v[6] * inv, v[7] * inv);
    const int kc = lane >> 1, hs = lane & 1;
    *(uint4*)(Fsw + (((size_t)(b * 128 + mt) * 24 + kc) << 9) + (hs * 32 + rl) * 8) = o;
  }
}

// ---------------------------------------------------------------------------
// K1b: normalize codes -> Csw[b][mt][kc(6)][lane(64)][8] (zero-padded to 96)
// + fp32 inverse norms. Runs AFTER knn_mfma: Csw overlays the dead Fsw region.
// ---------------------------------------------------------------------------
__global__ __launch_bounds__(64) void norm_c(const float* __restrict__ codes,
                                             unsigned short* __restrict__ Csw,
                                             float* __restrict__ invc) {
  const int row = blockIdx.x;
  const int lane = threadIdx.x;
  const int b = row >> 12, mt = (row >> 5) & 127, rl = row & 31;

  const float* c = codes + (size_t)row * 90;
  float cv[8];
#pragma unroll
  for (int e = 0; e < 8; ++e) cv[e] = 0.f;
  if (lane < 11) {
    float4 p0 = *(const float4*)(c + lane * 8);
    float4 p1 = *(const float4*)(c + lane * 8 + 4);
    cv[0] = p0.x; cv[1] = p0.y; cv[2] = p0.z; cv[3] = p0.w;
    cv[4] = p1.x; cv[5] = p1.y; cv[6] = p1.z; cv[7] = p1.w;
  } else if (lane == 11) {
    cv[0] = c[88]; cv[1] = c[89];
  }
  float cs = 0.f;
#pragma unroll
  for (int e = 0; e < 8; ++e) cs = fmaf(cv[e], cv[e], cs);
#pragma unroll
  for (int m = 1; m <= 32; m <<= 1) cs += __shfl_xor(cs, m, 64);
  const float cinv = rsqrtf(cs + 1e-8f);
  if (lane < 12) {
    uint4 o;
    o.x = bf16pack(cv[0] * cinv, cv[1] * cinv);
    o.y = bf16pack(cv[2] * cinv, cv[3] * cinv);
    o.z = bf16pack(cv[4] * cinv, cv[5] * cinv);
    o.w = bf16pack(cv[6] * cinv, cv[7] * cinv);
    const int kc = lane >> 1, hs = lane & 1;
    *(uint4*)(Csw + (((size_t)(b * 128 + mt) * 6 + kc) << 9) + (hs * 32 + rl) * 8) = o;
  }
  if (lane == 0) invc[row] = cinv;
}

// ---------------------------------------------------------------------------
// K2: feature similarities via 32x32x16 bf16 MFMA (swapped: D[m][q]) + top-7.
// Grid 1024 = qt(128) x quarter(4) x b(2), 256-thr / 4-wave blocks; each wave
// sweeps 8 tiles (t0 = p*32 + w*8). Round-13 structure: double-accumulator
// pipeline -- tile t's top-7 epilogue runs interleaved inside tile t+1's
// load/MFMA schedule (covers L2 latency with VALU), and the epilogue is
// filtered by a wave-uniform threshold test (skip cas7 when no lane beats
// the current 7th-best).
// ---------------------------------------------------------------------------
__global__ __launch_bounds__(256, 1) void knn_mfma(const unsigned short* __restrict__ Fsw,
                                                   unsigned* __restrict__ cand) {
  __shared__ unsigned ckey[4][32][7];
  const int g = blockIdx.x;              // 0..1023
  const int b = g & 1;
  const int p = (g >> 1) & 3;            // m-quarter
  const int qt = g >> 3;                 // q-tile 0..127
  const int q0 = qt * 32;
  const int tid = threadIdx.x;
  const int w = tid >> 6;                // 0..3
  const int lane = tid & 63;
  const int lo = lane & 31, hi4 = (lane >> 5) * 4;
  const unsigned short* Fb = Fsw + (size_t)b * 128 * 24 * 512;

  bf16x8 bfr[24];
  {
    const unsigned short* qb = Fb + ((size_t)qt * 24) * 512 + lane * 8;
#pragma unroll
    for (int t = 0; t < 24; ++t) bfr[t] = *(const bf16x8*)(qb + t * 512);
#pragma unroll
    for (int t = 0; t < 24; ++t) KEEP(bfr[t]);
  }
  unsigned s7[7];
#pragma unroll
  for (int t = 0; t < 7; ++t) s7[t] = KSENT;

  const int t0 = p * 32 + w * 8;         // wave's first global tile (8 tiles)
  const unsigned short* ab = Fb + ((size_t)t0 * 24) * 512 + lane * 8;

  bf16x8 a0[12], a1[12];

#define LOADA0(MT)                                                             \
  { const unsigned short* ar_ = ab + (size_t)(MT) * 24 * 512;                  \
    _Pragma("unroll")                                                          \
    for (int t = 0; t < 12; ++t) a0[t] = *(const bf16x8*)(ar_ + t * 512);      \
    _Pragma("unroll")                                                          \
    for (int t = 0; t < 12; ++t) KEEP(a0[t]); }

#define LOADA1(MT)                                                             \
  { const unsigned short* ar_ = ab + (size_t)(MT) * 24 * 512;                  \
    _Pragma("unroll")                                                          \
    for (int t = 0; t < 12; ++t) a1[t] = *(const bf16x8*)(ar_ + (12 + t) * 512); \
    _Pragma("unroll")                                                          \
    for (int t = 0; t < 12; ++t) KEEP(a1[t]); }

// filtered half-epilogue: values R0..R0+7 of ACC (tile MT) into s7
#define EPI8(ACC, MT, R0)                                                      \
  { const float thr_ = unpackkey(s7[6]);                                       \
    const int mb_ = (t0 + (MT)) * 32 + hi4;                                    \
    _Pragma("unroll")                                                          \
    for (int r = (R0); r < (R0) + 8; ++r) {                                    \
      const float v_ = ACC[r];                                                 \
      if (__any(v_ > thr_))                                                    \
        cas7(packkey(v_, mb_ + (r & 3) + 8 * (r >> 2)), s7);                   \
    } }

// tile MT -> ACC, with tile PMT's epilogue (on PACC) interleaved
#define TILE(ACC, MT, PACC, PMT, DOEPI)                                        \
  LOADA1(MT)                                                                   \
  ACC = zero16();                                                              \
  _Pragma("unroll")                                                            \
  for (int t = 0; t < 12; ++t)                                                 \
    ACC = __builtin_amdgcn_mfma_f32_32x32x16_bf16(a0[t], bfr[t], ACC, 0, 0, 0); \
  if (DOEPI) { EPI8(PACC, PMT, 0) }                                            \
  if ((MT) + 1 < 8) { LOADA0((MT) + 1) }                                       \
  _Pragma("unroll")                                                            \
  for (int t = 0; t < 12; ++t)                                                 \
    ACC = __builtin_amdgcn_mfma_f32_32x32x16_bf16(a1[t], bfr[12 + t], ACC, 0, 0, 0); \
  if (DOEPI) { EPI8(PACC, PMT, 8) }

  LOADA0(0)
  f32x16 accA, accB;
  TILE(accA, 0, accB, 0, 0)
  TILE(accB, 1, accA, 0, 1)
  TILE(accA, 2, accB, 1, 1)
  TILE(accB, 3, accA, 2, 1)
  TILE(accA, 4, accB, 3, 1)
  TILE(accB, 5, accA, 4, 1)
  TILE(accA, 6, accB, 5, 1)
  TILE(accB, 7, accA, 6, 1)
  EPI8(accB, 7, 0)
  EPI8(accB, 7, 8)
#undef TILE
#undef EPI8
#undef LOADA0
#undef LOADA1

  // merge lane pairs (lane, lane^32) covering the same q-column
#pragma unroll
  for (int t = 0; t < 7; ++t) {
    const unsigned ov = (unsigned)__shfl_xor((int)s7[t], 32, 64);
    cas7(ov, s7);
  }
  if (lane < 32) {
#pragma unroll
    for (int t = 0; t < 7; ++t) ckey[w][lo][t] = s7[t];
  }
  __syncthreads();

  // block merge: 32 threads, one q each, scan 4 waves x 7 keys -> cand
  if (tid < 32) {
    unsigned fs[7];
#pragma unroll
    for (int t = 0; t < 7; ++t) fs[t] = KSENT;
    for (int w2 = 0; w2 < 4; ++w2)
#pragma unroll
      for (int t = 0; t < 7; ++t) cas7(ckey[w2][tid][t], fs);
    unsigned* o = cand + ((size_t)((p * 2 + b) * NPTS) + q0 + tid) * 7;
#pragma unroll
    for (int t = 0; t < 7; ++t) o[t] = fs[t];
  }
}

// ---------------------------------------------------------------------------
// K3: code similarities -> partial exp-sums (fixed shift 10 = self logit) +
// depth-Gaussian weighted sum. 1024 blocks / 8 tiles per wave.
// ---------------------------------------------------------------------------
__global__ __launch_bounds__(256, 1) void lse_depth(const unsigned short* __restrict__ Csw,
                                                    const float* __restrict__ depth,
                                                    float* __restrict__ slse_part,
                                                    float* __restrict__ dpart) {
  __shared__ float lsep[4][32];
  __shared__ float depp[4];
  const int g = blockIdx.x;              // 0..1023
  const int b = g & 1;
  const int p = (g >> 1) & 3;
  const int qt = g >> 3;
  const int q0 = qt * 32;
  const int tid = threadIdx.x;
  const int w = tid >> 6;                // 0..3
  const int lane = tid & 63;
  const int lo = lane & 31, hi4 = (lane >> 5) * 4;
  const unsigned short* Cb = Csw + (size_t)b * 128 * 6 * 512;
  const float* db = depth + b * NPTS;

  bf16x8 bfr[6];
  {
    const unsigned short* qb = Cb + ((size_t)qt * 6) * 512 + lane * 8;
#pragma unroll
    for (int t = 0; t < 6; ++t) bfr[t] = *(const bf16x8*)(qb + t * 512);
#pragma unroll
    for (int t = 0; t < 6; ++t) KEEP(bfr[t]);
  }
  const float dq = db[q0 + lo];
  float slse = 0.f, sdep = 0.f;

  const int t0 = p * 32 + w * 8;         // 8 tiles per wave
  const unsigned short* ab = Cb + ((size_t)t0 * 6) * 512 + lane * 8;

  bf16x8 a0[6], a1[6];
#pragma unroll
  for (int t = 0; t < 6; ++t) a0[t] = *(const bf16x8*)(ab + t * 512);
#pragma unroll
  for (int t = 0; t < 6; ++t) KEEP(a0[t]);

#define PROC3(A, GT)                                                           \
  {                                                                            \
    f32x16 acc = zero16();                                                     \
    _Pragma("unroll")                                                          \
    for (int t = 0; t < 6; ++t)                                                \
      acc = __builtin_amdgcn_mfma_f32_32x32x16_bf16(A[t], bfr[t], acc, 0, 0, 0); \
    float dvv[16];                                                             \
    _Pragma("unroll")                                                          \
    for (int k = 0; k < 4; ++k) {                                              \
      float4 dv = *(const float4*)(db + (GT) * 32 + hi4 + 8 * k);              \
      dvv[k * 4 + 0] = dv.x; dvv[k * 4 + 1] = dv.y;                            \
      dvv[k * 4 + 2] = dv.z; dvv[k * 4 + 3] = dv.w;                            \
    }                                                                          \
    _Pragma("unroll")                                                          \
    for (int r = 0; r < 16; ++r) {                                             \
      const float s = acc[r];                                                  \
      const float dd = dq - dvv[r];                                            \
      sdep += __expf(-2.f * dd * dd) * (1.f - s);                              \
      slse += __expf(fmaf(s, 10.f, -10.f));                                    \
    }                                                                          \
  }

  for (int mt = 0; mt < 8; mt += 2) {
    {
      const unsigned short* ar = ab + (size_t)(mt + 1) * 6 * 512;
#pragma unroll
      for (int t = 0; t < 6; ++t) a1[t] = *(const bf16x8*)(ar + t * 512);
#pragma unroll
      for (int t = 0; t < 6; ++t) KEEP(a1[t]);
    }
    PROC3(a0, t0 + mt)
    if (mt + 2 < 8) {
      const unsigned short* ar = ab + (size_t)(mt + 2) * 6 * 512;
#pragma unroll
      for (int t = 0; t < 6; ++t) a0[t] = *(const bf16x8*)(ar + t * 512);
#pragma unroll
      for (int t = 0; t < 6; ++t) KEEP(a0[t]);
    }
    PROC3(a1, t0 + mt + 1)
  }
#undef PROC3

  slse += __shfl_xor(slse, 32, 64);
  if (lane < 32) lsep[w][lo] = slse;
#pragma unroll
  for (int m = 1; m <= 32; m <<= 1) sdep += __shfl_xor(sdep, m, 64);
  if (lane == 0) depp[w] = sdep;
  __syncthreads();
  if (tid < 32) {
    float tot = 0.f;
#pragma unroll
    for (int w2 = 0; w2 < 4; ++w2) tot += lsep[w2][tid];
    slse_part[(size_t)((p * 2 + b) * NPTS) + q0 + tid] = tot;   // raw exp-sum
  }
  if (tid == 32) {
    float d = 0.f;
#pragma unroll
    for (int w2 = 0; w2 < 4; ++w2) d += depp[w2];
    dpart[g] = d;
  }
}

// ---------------------------------------------------------------------------
// K4: merge the four quarter-candidate lists, force self, then 7 positive-pair
// code dots in FP32 from raw codes. One wave per row.
// ---------------------------------------------------------------------------
__global__ __launch_bounds__(64) void gather_pos(const float* __restrict__ codes,
                                                 const float* __restrict__ invc,
                                                 const unsigned* __restrict__ cand,
                                                 float* __restrict__ gpart) {
  const int n = blockIdx.x;              // 0..8191 (global row)
  const int b = n >> 12, q = n & 4095;
  const int lane = threadIdx.x;

  // merge 4 x 7 packed keys (all lanes redundantly; broadcast loads)
  unsigned s[7];
#pragma unroll
  for (int t = 0; t < 7; ++t) s[t] = KSENT;
#pragma unroll
  for (int pp = 0; pp < 4; ++pp) {
    const unsigned* cp = cand + ((size_t)((pp * 2 + b) * NPTS) + q) * 7;
#pragma unroll
    for (int t = 0; t < 7; ++t) cas7(cp[t], s);
  }
  // FORCE self (self-sim = 1 is always the reference max)
  bool has = false;
#pragma unroll
  for (int t = 0; t < 7; ++t) has = has || ((s[t] & 4095u) == (unsigned)q);
  if (!has) s[6] = (unsigned)q;

  const float* cn = codes + (size_t)n * 90;
  float2 a = make_float2(0.f, 0.f);
  if (lane < 45) a = *(const float2*)(cn + lane * 2);
  const float inva = invc[n];
  float ssum = 0.f;
#pragma unroll
  for (int k = 0; k < 7; ++k) {
    const int m = (int)(s[k] & 4095u);
    const float* cm = codes + ((size_t)(b << 12) + m) * 90;
    float2 bb = make_float2(0.f, 0.f);
    if (lane < 45) bb = *(const float2*)(cm + lane * 2);
    float p = fmaf(a.x, bb.x, a.y * bb.y);
#pragma unroll
    for (int w = 1; w <= 32; w <<= 1) p += __shfl_xor(p, w, 64);
    ssum += p * inva * invc[(b << 12) + m];
  }
  if (lane == 0) gpart[n] = ssum;
}

// ---------------------------------------------------------------------------
// K5: finalize -> (l_stego, l_depthg, total). Log of merged exp-sums here.
// ---------------------------------------------------------------------------
__global__ __launch_bounds__(256) void finalize(const float* __restrict__ slse_part,
                                                const float* __restrict__ gpart,
                                                const float* __restrict__ dpart,
                                                float* __restrict__ out) {
  const int tid = threadIdx.x;
  float s1 = 0.f, s2 = 0.f;
  for (int n = tid; n < 2 * NPTS; n += 256) {
    const int b = n >> 12, q = n & 4095;
    float pz = 0.f;
#pragma unroll
    for (int pp = 0; pp < 4; ++pp) pz += slse_part[(pp * 2 + b) * NPTS + q];
    s1 += 10.f + __logf(pz);
    s2 += gpart[n];
  }
  float s3 = 0.f;
#pragma unroll
  for (int k = 0; k < 4; ++k) s3 += dpart[tid + k * 256];
  __shared__ float r1[256], r2[256], r3[256];
  r1[tid] = s1; r2[tid] = s2; r3[tid] = s3;
  __syncthreads();
  for (int s = 128; s > 0; s >>= 1) {
    if (tid < s) { r1[tid] += r1[tid + s]; r2[tid] += r2[tid + s]; r3[tid] += r3[tid + s]; }
    __syncthreads();
  }
  if (tid == 0) {
    const float l_st = (7.f * r1[0] - 10.f * r2[0]) / 57344.f;
    const float l_dp = r3[0] / 33554432.f;
    out[0] = l_st;
    out[1] = l_dp;
    out[2] = l_st + 0.3f * l_dp;
  }
}

// ---------------------------------------------------------------------------
// ws layout (peak 7.24 MB <= proven-safe 8.19 MB):
//   invc      @ 0        (32768)    [norm_c .. gather]
//   cand      @ 32768    (917504)   [knn .. gather]
//   Fsw       @ 950272   (6291456)  [norm_f .. knn]  -- dead after knn:
//     Csw       @ 950272  (1572864)  [norm_c .. lse]  (overlays dead Fsw)
//     slse_part @ 2523136 (131072)   [lse .. finalize]
//     dpart     @ 2654208 (4096)
//     gpart     @ 2658304 (32768)
// ---------------------------------------------------------------------------
extern "C" void kernel_launch(void* const* d_in, const int* in_sizes, int n_in,
                              void* d_out, int out_size, void* d_ws, size_t ws_size,
                              hipStream_t stream) {
  (void)in_sizes; (void)n_in; (void)out_size; (void)ws_size;
  const float* codes = (const float*)d_in[0];   // (B,N,90)
  const float* feats = (const float*)d_in[1];   // (B,N,384)
  const float* depth = (const float*)d_in[2];   // (B,N)
  float* out = (float*)d_out;

  char* ws = (char*)d_ws;
  float*    invc      = (float*)ws;
  unsigned* cand      = (unsigned*)(ws + 32768);
  unsigned short* Fsw = (unsigned short*)(ws + 950272);
  unsigned short* Csw = (unsigned short*)(ws + 950272);
  float*    slse_part = (float*)(ws + 2523136);
  float*    dpart     = (float*)(ws + 2654208);
  float*    gpart     = (float*)(ws + 2658304);

  norm_f<<<2 * NPTS, 64, 0, stream>>>(feats, Fsw);
  knn_mfma<<<1024, 256, 0, stream>>>(Fsw, cand);
  norm_c<<<2 * NPTS, 64, 0, stream>>>(codes, Csw, invc);   // Csw overlays dead Fsw
  lse_depth<<<1024, 256, 0, stream>>>(Csw, depth, slse_part, dpart);
  gather_pos<<<2 * NPTS, 64, 0, stream>>>(codes, invc, cand, gpart);
  finalize<<<1, 256, 0, stream>>>(slse_part, gpart, dpart, out);
}

// Round 14
// 109.060 us; speedup vs baseline: 1.1936x; 1.1936x over previous
//
#include <hip/hip_runtime.h>
#include <math.h>

#define NPTS 4096

typedef __attribute__((ext_vector_type(8))) short bf16x8;
typedef __attribute__((ext_vector_type(16))) float f32x16;

// liveness pin: forbid rematerialization / load sinking (round-5 lesson)
#define KEEP(x) asm volatile("" : "+v"(x))

__device__ __forceinline__ f32x16 zero16() {
  f32x16 z;
#pragma unroll
  for (int i = 0; i < 16; ++i) z[i] = 0.f;
  return z;
}

// monotonic sortable key (ascending with float value) with 12-bit m index
// embedded in the low mantissa bits (clearing them perturbs the compared
// value by ~2^-12 relative -- far below the bf16 noise already tolerated).
__device__ __forceinline__ unsigned packkey(float x, int m) {
  unsigned u = __float_as_uint(x);
  unsigned key = u ^ ((unsigned)((int)u >> 31) | 0x80000000u);
  return (key & 0xFFFFF000u) | (unsigned)m;
}

// cascade insert into sorted-descending 7-array: 7 umax + 7 umin, no branches
__device__ __forceinline__ void cas7(unsigned v, unsigned* s) {
#pragma unroll
  for (int t = 0; t < 7; ++t) {
    const unsigned hi = s[t] >= v ? s[t] : v;
    const unsigned lo = s[t] >= v ? v : s[t];
    s[t] = hi;
    v = lo;
  }
}

#define KSENT 0u   // sentinel key (no threshold filter -> 0 is safe)

__device__ __forceinline__ unsigned bf16pack(float a, float b) {
  unsigned ua = __float_as_uint(a); ua = (ua + 0x7FFFu + ((ua >> 16) & 1u)) >> 16;
  unsigned ub = __float_as_uint(b); ub = (ub + 0x7FFFu + ((ub >> 16) & 1u)) >> 16;
  return ua | (ub << 16);
}

// ---------------------------------------------------------------------------
// K1a: normalize features -> fragment-major bf16 Fsw[b][mt][kc(24)][lane(64)][8]
// ---------------------------------------------------------------------------
__global__ __launch_bounds__(64) void norm_f(const float* __restrict__ feats,
                                             unsigned short* __restrict__ Fsw) {
  const int row = blockIdx.x;            // 0 .. 8191
  const int lane = threadIdx.x;
  const int b = row >> 12, mt = (row >> 5) & 127, rl = row & 31;

  const float* f = feats + (size_t)row * 384;
  float v[8];
  float ss = 0.f;
  if (lane < 48) {
    float4 p0 = *(const float4*)(f + lane * 8);
    float4 p1 = *(const float4*)(f + lane * 8 + 4);
    v[0] = p0.x; v[1] = p0.y; v[2] = p0.z; v[3] = p0.w;
    v[4] = p1.x; v[5] = p1.y; v[6] = p1.z; v[7] = p1.w;
#pragma unroll
    for (int e = 0; e < 8; ++e) ss = fmaf(v[e], v[e], ss);
  }
#pragma unroll
  for (int m = 1; m <= 32; m <<= 1) ss += __shfl_xor(ss, m, 64);
  const float inv = rsqrtf(ss + 1e-8f);
  if (lane < 48) {
    uint4 o;
    o.x = bf16pack(v[0] * inv, v[1] * inv);
    o.y = bf16pack(v[2] * inv, v[3] * inv);
    o.z = bf16pack(v[4] * inv, v[5] * inv);
    o.w = bf16pack(v[6] * inv, v[7] * inv);
    const int kc = lane >> 1, hs = lane & 1;
    *(uint4*)(Fsw + (((size_t)(b * 128 + mt) * 24 + kc) << 9) + (hs * 32 + rl) * 8) = o;
  }
}

// ---------------------------------------------------------------------------
// K1b: normalize codes -> Csw[b][mt][kc(6)][lane(64)][8] (zero-padded to 96)
// + fp32 inverse norms. Runs AFTER knn_mfma: Csw overlays the dead Fsw region.
// ---------------------------------------------------------------------------
__global__ __launch_bounds__(64) void norm_c(const float* __restrict__ codes,
                                             unsigned short* __restrict__ Csw,
                                             float* __restrict__ invc) {
  const int row = blockIdx.x;
  const int lane = threadIdx.x;
  const int b = row >> 12, mt = (row >> 5) & 127, rl = row & 31;

  const float* c = codes + (size_t)row * 90;
  float cv[8];
#pragma unroll
  for (int e = 0; e < 8; ++e) cv[e] = 0.f;
  if (lane < 11) {
    float4 p0 = *(const float4*)(c + lane * 8);
    float4 p1 = *(const float4*)(c + lane * 8 + 4);
    cv[0] = p0.x; cv[1] = p0.y; cv[2] = p0.z; cv[3] = p0.w;
    cv[4] = p1.x; cv[5] = p1.y; cv[6] = p1.z; cv[7] = p1.w;
  } else if (lane == 11) {
    cv[0] = c[88]; cv[1] = c[89];
  }
  float cs = 0.f;
#pragma unroll
  for (int e = 0; e < 8; ++e) cs = fmaf(cv[e], cv[e], cs);
#pragma unroll
  for (int m = 1; m <= 32; m <<= 1) cs += __shfl_xor(cs, m, 64);
  const float cinv = rsqrtf(cs + 1e-8f);
  if (lane < 12) {
    uint4 o;
    o.x = bf16pack(cv[0] * cinv, cv[1] * cinv);
    o.y = bf16pack(cv[2] * cinv, cv[3] * cinv);
    o.z = bf16pack(cv[4] * cinv, cv[5] * cinv);
    o.w = bf16pack(cv[6] * cinv, cv[7] * cinv);
    const int kc = lane >> 1, hs = lane & 1;
    *(uint4*)(Csw + (((size_t)(b * 128 + mt) * 6 + kc) << 9) + (hs * 32 + rl) * 8) = o;
  }
  if (lane == 0) invc[row] = cinv;
}

// ---------------------------------------------------------------------------
// K2: feature similarities via 32x32x16 bf16 MFMA (swapped: D[m][q]) + top-7.
// Grid 1024 = qt(128) x quarter(4) x b(2), 256-thr / 4-wave blocks; each wave
// sweeps 8 tiles (t0 = p*32 + w*8). Round-14: half-carried epilogue --
// acc[0..7] inserted right after the tile's bursts, acc[8..15] carried in 8
// registers and inserted at the top of the NEXT tile, inside the a1-load
// shadow (covers ~300cy of L2 latency with VALU). No double-acc (r13's +28
// VGPR killed occupancy), no __any filter (wave-any take-prob ~= 1, useless).
// ---------------------------------------------------------------------------
__global__ __launch_bounds__(256, 1) void knn_mfma(const unsigned short* __restrict__ Fsw,
                                                   unsigned* __restrict__ cand) {
  __shared__ unsigned ckey[4][32][7];
  const int g = blockIdx.x;              // 0..1023
  const int b = g & 1;
  const int p = (g >> 1) & 3;            // m-quarter
  const int qt = g >> 3;                 // q-tile 0..127
  const int q0 = qt * 32;
  const int tid = threadIdx.x;
  const int w = tid >> 6;                // 0..3
  const int lane = tid & 63;
  const int lo = lane & 31, hi4 = (lane >> 5) * 4;
  const unsigned short* Fb = Fsw + (size_t)b * 128 * 24 * 512;

  bf16x8 bfr[24];
  {
    const unsigned short* qb = Fb + ((size_t)qt * 24) * 512 + lane * 8;
#pragma unroll
    for (int t = 0; t < 24; ++t) bfr[t] = *(const bf16x8*)(qb + t * 512);
#pragma unroll
    for (int t = 0; t < 24; ++t) KEEP(bfr[t]);
  }
  unsigned s7[7];
#pragma unroll
  for (int t = 0; t < 7; ++t) s7[t] = KSENT;

  const int t0 = p * 32 + w * 8;         // wave's first global tile (8 tiles)
  const unsigned short* ab = Fb + ((size_t)t0 * 24) * 512 + lane * 8;

  bf16x8 a0[12], a1[12];
  float cr[8];                            // carried half-epilogue values
  int mbprev = 0;

  {
#pragma unroll
    for (int t = 0; t < 12; ++t) a0[t] = *(const bf16x8*)(ab + t * 512);
#pragma unroll
    for (int t = 0; t < 12; ++t) KEEP(a0[t]);
  }

#pragma unroll
  for (int mt = 0; mt < 8; ++mt) {
    const unsigned short* art = ab + (size_t)mt * 24 * 512;
    // issue second K-half loads of this tile
#pragma unroll
    for (int t = 0; t < 12; ++t) a1[t] = *(const bf16x8*)(art + (12 + t) * 512);
#pragma unroll
    for (int t = 0; t < 12; ++t) KEEP(a1[t]);
    // carried epilogue from previous tile -- runs in the a1 load shadow
    if (mt > 0) {
#pragma unroll
      for (int i = 0; i < 8; ++i)
        cas7(packkey(cr[i], mbprev + 16 + (i & 3) + 8 * (i >> 2)), s7);
    }
    f32x16 acc = zero16();
#pragma unroll
    for (int t = 0; t < 12; ++t)
      acc = __builtin_amdgcn_mfma_f32_32x32x16_bf16(a0[t], bfr[t], acc, 0, 0, 0);
    if (mt + 1 < 8) {
      const unsigned short* arn = ab + (size_t)(mt + 1) * 24 * 512;
#pragma unroll
      for (int t = 0; t < 12; ++t) a0[t] = *(const bf16x8*)(arn + t * 512);
#pragma unroll
      for (int t = 0; t < 12; ++t) KEEP(a0[t]);
    }
#pragma unroll
    for (int t = 0; t < 12; ++t)
      acc = __builtin_amdgcn_mfma_f32_32x32x16_bf16(a1[t], bfr[12 + t], acc, 0, 0, 0);
    const int mb = (t0 + mt) * 32 + hi4;
    // first half-epilogue now; second half carried into next tile
#pragma unroll
    for (int r = 0; r < 8; ++r)
      cas7(packkey(acc[r], mb + (r & 3) + 8 * (r >> 2)), s7);
#pragma unroll
    for (int i = 0; i < 8; ++i) cr[i] = acc[8 + i];
    mbprev = mb;
  }
  // drain the last carry
#pragma unroll
  for (int i = 0; i < 8; ++i)
    cas7(packkey(cr[i], mbprev + 16 + (i & 3) + 8 * (i >> 2)), s7);

  // merge lane pairs (lane, lane^32) covering the same q-column
#pragma unroll
  for (int t = 0; t < 7; ++t) {
    const unsigned ov = (unsigned)__shfl_xor((int)s7[t], 32, 64);
    cas7(ov, s7);
  }
  if (lane < 32) {
#pragma unroll
    for (int t = 0; t < 7; ++t) ckey[w][lo][t] = s7[t];
  }
  __syncthreads();

  // block merge: 32 threads, one q each, scan 4 waves x 7 keys -> cand
  if (tid < 32) {
    unsigned fs[7];
#pragma unroll
    for (int t = 0; t < 7; ++t) fs[t] = KSENT;
    for (int w2 = 0; w2 < 4; ++w2)
#pragma unroll
      for (int t = 0; t < 7; ++t) cas7(ckey[w2][tid][t], fs);
    unsigned* o = cand + ((size_t)((p * 2 + b) * NPTS) + q0 + tid) * 7;
#pragma unroll
    for (int t = 0; t < 7; ++t) o[t] = fs[t];
  }
}

// ---------------------------------------------------------------------------
// K3: code similarities -> partial exp-sums (fixed shift 10 = self logit) +
// depth-Gaussian weighted sum. 1024 blocks / 8 tiles per wave.
// ---------------------------------------------------------------------------
__global__ __launch_bounds__(256, 1) void lse_depth(const unsigned short* __restrict__ Csw,
                                                    const float* __restrict__ depth,
                                                    float* __restrict__ slse_part,
                                                    float* __restrict__ dpart) {
  __shared__ float lsep[4][32];
  __shared__ float depp[4];
  const int g = blockIdx.x;              // 0..1023
  const int b = g & 1;
  const int p = (g >> 1) & 3;
  const int qt = g >> 3;
  const int q0 = qt * 32;
  const int tid = threadIdx.x;
  const int w = tid >> 6;                // 0..3
  const int lane = tid & 63;
  const int lo = lane & 31, hi4 = (lane >> 5) * 4;
  const unsigned short* Cb = Csw + (size_t)b * 128 * 6 * 512;
  const float* db = depth + b * NPTS;

  bf16x8 bfr[6];
  {
    const unsigned short* qb = Cb + ((size_t)qt * 6) * 512 + lane * 8;
#pragma unroll
    for (int t = 0; t < 6; ++t) bfr[t] = *(const bf16x8*)(qb + t * 512);
#pragma unroll
    for (int t = 0; t < 6; ++t) KEEP(bfr[t]);
  }
  const float dq = db[q0 + lo];
  float slse = 0.f, sdep = 0.f;

  const int t0 = p * 32 + w * 8;         // 8 tiles per wave
  const unsigned short* ab = Cb + ((size_t)t0 * 6) * 512 + lane * 8;

  bf16x8 a0[6], a1[6];
#pragma unroll
  for (int t = 0; t < 6; ++t) a0[t] = *(const bf16x8*)(ab + t * 512);
#pragma unroll
  for (int t = 0; t < 6; ++t) KEEP(a0[t]);

#define PROC3(A, GT)                                                           \
  {                                                                            \
    f32x16 acc = zero16();                                                     \
    _Pragma("unroll")                                                          \
    for (int t = 0; t < 6; ++t)                                                \
      acc = __builtin_amdgcn_mfma_f32_32x32x16_bf16(A[t], bfr[t], acc, 0, 0, 0); \
    float dvv[16];                                                             \
    _Pragma("unroll")                                                          \
    for (int k = 0; k < 4; ++k) {                                              \
      float4 dv = *(const float4*)(db + (GT) * 32 + hi4 + 8 * k);              \
      dvv[k * 4 + 0] = dv.x; dvv[k * 4 + 1] = dv.y;                            \
      dvv[k * 4 + 2] = dv.z; dvv[k * 4 + 3] = dv.w;                            \
    }                                                                          \
    _Pragma("unroll")                                                          \
    for (int r = 0; r < 16; ++r) {                                             \
      const float s = acc[r];                                                  \
      const float dd = dq - dvv[r];                                            \
      sdep += __expf(-2.f * dd * dd) * (1.f - s);                              \
      slse += __expf(fmaf(s, 10.f, -10.f));                                    \
    }                                                                          \
  }

  for (int mt = 0; mt < 8; mt += 2) {
    {
      const unsigned short* ar = ab + (size_t)(mt + 1) * 6 * 512;
#pragma unroll
      for (int t = 0; t < 6; ++t) a1[t] = *(const bf16x8*)(ar + t * 512);
#pragma unroll
      for (int t = 0; t < 6; ++t) KEEP(a1[t]);
    }
    PROC3(a0, t0 + mt)
    if (mt + 2 < 8) {
      const unsigned short* ar = ab + (size_t)(mt + 2) * 6 * 512;
#pragma unroll
      for (int t = 0; t < 6; ++t) a0[t] = *(const bf16x8*)(ar + t * 512);
#pragma unroll
      for (int t = 0; t < 6; ++t) KEEP(a0[t]);
    }
    PROC3(a1, t0 + mt + 1)
  }
#undef PROC3

  slse += __shfl_xor(slse, 32, 64);
  if (lane < 32) lsep[w][lo] = slse;
#pragma unroll
  for (int m = 1; m <= 32; m <<= 1) sdep += __shfl_xor(sdep, m, 64);
  if (lane == 0) depp[w] = sdep;
  __syncthreads();
  if (tid < 32) {
    float tot = 0.f;
#pragma unroll
    for (int w2 = 0; w2 < 4; ++w2) tot += lsep[w2][tid];
    slse_part[(size_t)((p * 2 + b) * NPTS) + q0 + tid] = tot;   // raw exp-sum
  }
  if (tid == 32) {
    float d = 0.f;
#pragma unroll
    for (int w2 = 0; w2 < 4; ++w2) d += depp[w2];
    dpart[g] = d;
  }
}

// ---------------------------------------------------------------------------
// K4: merge the four quarter-candidate lists, force self, then 7 positive-pair
// code dots in FP32 from raw codes. One wave per row.
// ---------------------------------------------------------------------------
__global__ __launch_bounds__(64) void gather_pos(const float* __restrict__ codes,
                                                 const float* __restrict__ invc,
                                                 const unsigned* __restrict__ cand,
                                                 float* __restrict__ gpart) {
  const int n = blockIdx.x;              // 0..8191 (global row)
  const int b = n >> 12, q = n & 4095;
  const int lane = threadIdx.x;

  // merge 4 x 7 packed keys (all lanes redundantly; broadcast loads)
  unsigned s[7];
#pragma unroll
  for (int t = 0; t < 7; ++t) s[t] = KSENT;
#pragma unroll
  for (int pp = 0; pp < 4; ++pp) {
    const unsigned* cp = cand + ((size_t)((pp * 2 + b) * NPTS) + q) * 7;
#pragma unroll
    for (int t = 0; t < 7; ++t) cas7(cp[t], s);
  }
  // FORCE self (self-sim = 1 is always the reference max)
  bool has = false;
#pragma unroll
  for (int t = 0; t < 7; ++t) has = has || ((s[t] & 4095u) == (unsigned)q);
  if (!has) s[6] = (unsigned)q;

  const float* cn = codes + (size_t)n * 90;
  float2 a = make_float2(0.f, 0.f);
  if (lane < 45) a = *(const float2*)(cn + lane * 2);
  const float inva = invc[n];
  float ssum = 0.f;
#pragma unroll
  for (int k = 0; k < 7; ++k) {
    const int m = (int)(s[k] & 4095u);
    const float* cm = codes + ((size_t)(b << 12) + m) * 90;
    float2 bb = make_float2(0.f, 0.f);
    if (lane < 45) bb = *(const float2*)(cm + lane * 2);
    float p = fmaf(a.x, bb.x, a.y * bb.y);
#pragma unroll
    for (int w = 1; w <= 32; w <<= 1) p += __shfl_xor(p, w, 64);
    ssum += p * inva * invc[(b << 12) + m];
  }
  if (lane == 0) gpart[n] = ssum;
}

// ---------------------------------------------------------------------------
// K5: finalize -> (l_stego, l_depthg, total). Log of merged exp-sums here.
// ---------------------------------------------------------------------------
__global__ __launch_bounds__(256) void finalize(const float* __restrict__ slse_part,
                                                const float* __restrict__ gpart,
                                                const float* __restrict__ dpart,
                                                float* __restrict__ out) {
  const int tid = threadIdx.x;
  float s1 = 0.f, s2 = 0.f;
  for (int n = tid; n < 2 * NPTS; n += 256) {
    const int b = n >> 12, q = n & 4095;
    float pz = 0.f;
#pragma unroll
    for (int pp = 0; pp < 4; ++pp) pz += slse_part[(pp * 2 + b) * NPTS + q];
    s1 += 10.f + __logf(pz);
    s2 += gpart[n];
  }
  float s3 = 0.f;
#pragma unroll
  for (int k = 0; k < 4; ++k) s3 += dpart[tid + k * 256];
  __shared__ float r1[256], r2[256], r3[256];
  r1[tid] = s1; r2[tid] = s2; r3[tid] = s3;
  __syncthreads();
  for (int s = 128; s > 0; s >>= 1) {
    if (tid < s) { r1[tid] += r1[tid + s]; r2[tid] += r2[tid + s]; r3[tid] += r3[tid + s]; }
    __syncthreads();
  }
  if (tid == 0) {
    const float l_st = (7.f * r1[0] - 10.f * r2[0]) / 57344.f;
    const float l_dp = r3[0] / 33554432.f;
    out[0] = l_st;
    out[1] = l_dp;
    out[2] = l_st + 0.3f * l_dp;
  }
}

// ---------------------------------------------------------------------------
// ws layout (peak 7.24 MB <= proven-safe 8.19 MB):
//   invc      @ 0        (32768)    [norm_c .. gather]
//   cand      @ 32768    (917504)   [knn .. gather]
//   Fsw       @ 950272   (6291456)  [norm_f .. knn]  -- dead after knn:
//     Csw       @ 950272  (1572864)  [norm_c .. lse]  (overlays dead Fsw)
//     slse_part @ 2523136 (131072)   [lse .. finalize]
//     dpart     @ 2654208 (4096)
//     gpart     @ 2658304 (32768)
// ---------------------------------------------------------------------------
extern "C" void kernel_launch(void* const* d_in, const int* in_sizes, int n_in,
                              void* d_out, int out_size, void* d_ws, size_t ws_size,
                              hipStream_t stream) {
  (void)in_sizes; (void)n_in; (void)out_size; (void)ws_size;
  const float* codes = (const float*)d_in[0];   // (B,N,90)
  const float* feats = (const float*)d_in[1];   // (B,N,384)
  const float* depth = (const float*)d_in[2];   // (B,N)
  float* out = (float*)d_out;

  char* ws = (char*)d_ws;
  float*    invc      = (float*)ws;
  unsigned* cand      = (unsigned*)(ws + 32768);
  unsigned short* Fsw = (unsigned short*)(ws + 950272);
  unsigned short* Csw = (unsigned short*)(ws + 950272);
  float*    slse_part = (float*)(ws + 2523136);
  float*    dpart     = (float*)(ws + 2654208);
  float*    gpart     = (float*)(ws + 2658304);

  norm_f<<<2 * NPTS, 64, 0, stream>>>(feats, Fsw);
  knn_mfma<<<1024, 256, 0, stream>>>(Fsw, cand);
  norm_c<<<2 * NPTS, 64, 0, stream>>>(codes, Csw, invc);   // Csw overlays dead Fsw
  lse_depth<<<1024, 256, 0, stream>>>(Csw, depth, slse_part, dpart);
  gather_pos<<<2 * NPTS, 64, 0, stream>>>(codes, invc, cand, gpart);
  finalize<<<1, 256, 0, stream>>>(slse_part, gpart, dpart, out);
}

// Round 15
// 92.648 us; speedup vs baseline: 1.4051x; 1.1771x over previous
//
#include <hip/hip_runtime.h>
#include <math.h>

#define NPTS 4096

typedef __attribute__((ext_vector_type(8))) short bf16x8;
typedef __attribute__((ext_vector_type(16))) float f32x16;
typedef long fp8x8;   // 8 fp8 bytes = one 32x32x16_fp8 A/B fragment per lane

// liveness pin: forbid rematerialization / load sinking (round-5 lesson)
#define KEEP(x) asm volatile("" : "+v"(x))

__device__ __forceinline__ f32x16 zero16() {
  f32x16 z;
#pragma unroll
  for (int i = 0; i < 16; ++i) z[i] = 0.f;
  return z;
}

// monotonic sortable key (ascending with float value) with 12-bit m index
// embedded in the low mantissa bits.
__device__ __forceinline__ unsigned packkey(float x, int m) {
  unsigned u = __float_as_uint(x);
  unsigned key = u ^ ((unsigned)((int)u >> 31) | 0x80000000u);
  return (key & 0xFFFFF000u) | (unsigned)m;
}

// cascade insert into sorted-descending 7-array: 7 umax + 7 umin, no branches
__device__ __forceinline__ void cas7(unsigned v, unsigned* s) {
#pragma unroll
  for (int t = 0; t < 7; ++t) {
    const unsigned hi = s[t] >= v ? s[t] : v;
    const unsigned lo = s[t] >= v ? v : s[t];
    s[t] = hi;
    v = lo;
  }
}

#define KSENT 0u

__device__ __forceinline__ unsigned bf16pack(float a, float b) {
  unsigned ua = __float_as_uint(a); ua = (ua + 0x7FFFu + ((ua >> 16) & 1u)) >> 16;
  unsigned ub = __float_as_uint(b); ub = (ub + 0x7FFFu + ((ub >> 16) & 1u)) >> 16;
  return ua | (ub << 16);
}

// ---------------------------------------------------------------------------
// K1a: normalize features -> fragment-major FP8 e4m3, scaled x8.
// Fsw8[b][mt][kc(24)][lane(64)][8 bytes]  (512 B per chunk)
// Only the KNN index set uses fp8; positives are recomputed in fp32 later.
// ---------------------------------------------------------------------------
__global__ __launch_bounds__(64) void norm_f(const float* __restrict__ feats,
                                             unsigned char* __restrict__ Fsw8) {
  const int row = blockIdx.x;            // 0 .. 8191
  const int lane = threadIdx.x;
  const int b = row >> 12, mt = (row >> 5) & 127, rl = row & 31;

  const float* f = feats + (size_t)row * 384;
  float v[8];
  float ss = 0.f;
  if (lane < 48) {
    float4 p0 = *(const float4*)(f + lane * 8);
    float4 p1 = *(const float4*)(f + lane * 8 + 4);
    v[0] = p0.x; v[1] = p0.y; v[2] = p0.z; v[3] = p0.w;
    v[4] = p1.x; v[5] = p1.y; v[6] = p1.z; v[7] = p1.w;
#pragma unroll
    for (int e = 0; e < 8; ++e) ss = fmaf(v[e], v[e], ss);
  }
#pragma unroll
  for (int m = 1; m <= 32; m <<= 1) ss += __shfl_xor(ss, m, 64);
  const float s8 = rsqrtf(ss + 1e-8f) * 8.0f;   // x8: e4m3 sweet spot
  if (lane < 48) {
    int w0 = __builtin_amdgcn_cvt_pk_fp8_f32(v[0] * s8, v[1] * s8, 0, 0);
    w0 = __builtin_amdgcn_cvt_pk_fp8_f32(v[2] * s8, v[3] * s8, w0, 1);
    int w1 = __builtin_amdgcn_cvt_pk_fp8_f32(v[4] * s8, v[5] * s8, 0, 0);
    w1 = __builtin_amdgcn_cvt_pk_fp8_f32(v[6] * s8, v[7] * s8, w1, 1);
    const int kc = lane >> 1, hs = lane & 1;
    uint2 o = make_uint2((unsigned)w0, (unsigned)w1);
    *(uint2*)(Fsw8 + (((size_t)(b * 128 + mt) * 24 + kc) << 9) + (hs * 32 + rl) * 8) = o;
  }
}

// ---------------------------------------------------------------------------
// K1b: normalize codes -> bf16 Csw[b][mt][kc(6)][lane(64)][8] (pad to 96)
// + fp32 inverse norms. Runs AFTER knn_mfma: Csw overlays the dead Fsw8.
// ---------------------------------------------------------------------------
__global__ __launch_bounds__(64) void norm_c(const float* __restrict__ codes,
                                             unsigned short* __restrict__ Csw,
                                             float* __restrict__ invc) {
  const int row = blockIdx.x;
  const int lane = threadIdx.x;
  const int b = row >> 12, mt = (row >> 5) & 127, rl = row & 31;

  const float* c = codes + (size_t)row * 90;
  float cv[8];
#pragma unroll
  for (int e = 0; e < 8; ++e) cv[e] = 0.f;
  if (lane < 11) {
    float4 p0 = *(const float4*)(c + lane * 8);
    float4 p1 = *(const float4*)(c + lane * 8 + 4);
    cv[0] = p0.x; cv[1] = p0.y; cv[2] = p0.z; cv[3] = p0.w;
    cv[4] = p1.x; cv[5] = p1.y; cv[6] = p1.z; cv[7] = p1.w;
  } else if (lane == 11) {
    cv[0] = c[88]; cv[1] = c[89];
  }
  float cs = 0.f;
#pragma unroll
  for (int e = 0; e < 8; ++e) cs = fmaf(cv[e], cv[e], cs);
#pragma unroll
  for (int m = 1; m <= 32; m <<= 1) cs += __shfl_xor(cs, m, 64);
  const float cinv = rsqrtf(cs + 1e-8f);
  if (lane < 12) {
    uint4 o;
    o.x = bf16pack(cv[0] * cinv, cv[1] * cinv);
    o.y = bf16pack(cv[2] * cinv, cv[3] * cinv);
    o.z = bf16pack(cv[4] * cinv, cv[5] * cinv);
    o.w = bf16pack(cv[6] * cinv, cv[7] * cinv);
    const int kc = lane >> 1, hs = lane & 1;
    *(uint4*)(Csw + (((size_t)(b * 128 + mt) * 6 + kc) << 9) + (hs * 32 + rl) * 8) = o;
  }
  if (lane == 0) invc[row] = cinv;
}

// ---------------------------------------------------------------------------
// K2: feature similarities via 32x32x16 FP8 MFMA (swapped: D[m][q]) + top-7.
// Exact round-12 schedule (verified 47 us) with fp8 operands: half the
// A-panel bytes (L2 floor 23 -> 11 us) and half the fragment VGPRs.
// Grid 1024 = qt(128) x quarter(4) x b(2), 256-thr / 4-wave blocks,
// t0 = p*32 + w*8 (8 tiles/wave). C/D layout is dtype-independent.
// ---------------------------------------------------------------------------
__global__ __launch_bounds__(256, 1) void knn_mfma(const unsigned char* __restrict__ Fsw8,
                                                   unsigned* __restrict__ cand) {
  __shared__ unsigned ckey[4][32][7];
  const int g = blockIdx.x;              // 0..1023
  const int b = g & 1;
  const int p = (g >> 1) & 3;            // m-quarter
  const int qt = g >> 3;                 // q-tile 0..127
  const int q0 = qt * 32;
  const int tid = threadIdx.x;
  const int w = tid >> 6;                // 0..3
  const int lane = tid & 63;
  const int lo = lane & 31, hi4 = (lane >> 5) * 4;
  const unsigned char* Fb = Fsw8 + (size_t)b * 128 * 24 * 512;

  fp8x8 bfr[24];
  {
    const unsigned char* qb = Fb + ((size_t)qt * 24) * 512 + lane * 8;
#pragma unroll
    for (int t = 0; t < 24; ++t) bfr[t] = *(const fp8x8*)(qb + t * 512);
#pragma unroll
    for (int t = 0; t < 24; ++t) KEEP(bfr[t]);
  }
  unsigned s7[7];
#pragma unroll
  for (int t = 0; t < 7; ++t) s7[t] = KSENT;

  const int t0 = p * 32 + w * 8;         // wave's first global tile (8 tiles)
  const unsigned char* ab = Fb + ((size_t)t0 * 24) * 512 + lane * 8;

  fp8x8 a0[12], a1[12];
#pragma unroll
  for (int t = 0; t < 12; ++t) a0[t] = *(const fp8x8*)(ab + t * 512);
#pragma unroll
  for (int t = 0; t < 12; ++t) KEEP(a0[t]);

  for (int mt = 0; mt < 8; ++mt) {
    const unsigned char* art = ab + (size_t)mt * 24 * 512;
#pragma unroll
    for (int t = 0; t < 12; ++t) a1[t] = *(const fp8x8*)(art + (12 + t) * 512);
#pragma unroll
    for (int t = 0; t < 12; ++t) KEEP(a1[t]);
    f32x16 acc = zero16();
#pragma unroll
    for (int t = 0; t < 12; ++t)
      acc = __builtin_amdgcn_mfma_f32_32x32x16_fp8_fp8(a0[t], bfr[t], acc, 0, 0, 0);
    if (mt + 1 < 8) {
      const unsigned char* arn = ab + (size_t)(mt + 1) * 24 * 512;
#pragma unroll
      for (int t = 0; t < 12; ++t) a0[t] = *(const fp8x8*)(arn + t * 512);
#pragma unroll
      for (int t = 0; t < 12; ++t) KEEP(a0[t]);
    }
#pragma unroll
    for (int t = 0; t < 12; ++t)
      acc = __builtin_amdgcn_mfma_f32_32x32x16_fp8_fp8(a1[t], bfr[12 + t], acc, 0, 0, 0);
    const int mb = (t0 + mt) * 32 + hi4;
#pragma unroll
    for (int r = 0; r < 16; ++r) {
      const int m = mb + (r & 3) + 8 * (r >> 2);
      cas7(packkey(acc[r], m), s7);
    }
  }

  // merge lane pairs (lane, lane^32) covering the same q-column
#pragma unroll
  for (int t = 0; t < 7; ++t) {
    const unsigned ov = (unsigned)__shfl_xor((int)s7[t], 32, 64);
    cas7(ov, s7);
  }
  if (lane < 32) {
#pragma unroll
    for (int t = 0; t < 7; ++t) ckey[w][lo][t] = s7[t];
  }
  __syncthreads();

  // block merge: 32 threads, one q each, scan 4 waves x 7 keys -> cand
  if (tid < 32) {
    unsigned fs[7];
#pragma unroll
    for (int t = 0; t < 7; ++t) fs[t] = KSENT;
    for (int w2 = 0; w2 < 4; ++w2)
#pragma unroll
      for (int t = 0; t < 7; ++t) cas7(ckey[w2][tid][t], fs);
    unsigned* o = cand + ((size_t)((p * 2 + b) * NPTS) + q0 + tid) * 7;
#pragma unroll
    for (int t = 0; t < 7; ++t) o[t] = fs[t];
  }
}

// ---------------------------------------------------------------------------
// K3: code similarities -> partial exp-sums (fixed shift 10 = self logit) +
// depth-Gaussian weighted sum. Round-10-verified shape: grid 512 = qt(128) x
// half(2) x b(2), 512-thr / 8-wave blocks, t0 = h*64 + w*8.
// ---------------------------------------------------------------------------
__global__ __launch_bounds__(512, 1) void lse_depth(const unsigned short* __restrict__ Csw,
                                                    const float* __restrict__ depth,
                                                    float* __restrict__ slse_part,
                                                    float* __restrict__ dpart) {
  __shared__ float lsep[8][32];
  __shared__ float depp[8];
  const int g = blockIdx.x;              // 0..511
  const int b = g & 1;
  const int h = (g >> 1) & 1;
  const int qt = g >> 2;
  const int q0 = qt * 32;
  const int tid = threadIdx.x;
  const int w = tid >> 6;
  const int lane = tid & 63;
  const int lo = lane & 31, hi4 = (lane >> 5) * 4;
  const unsigned short* Cb = Csw + (size_t)b * 128 * 6 * 512;
  const float* db = depth + b * NPTS;

  bf16x8 bfr[6];
  {
    const unsigned short* qb = Cb + ((size_t)qt * 6) * 512 + lane * 8;
#pragma unroll
    for (int t = 0; t < 6; ++t) bfr[t] = *(const bf16x8*)(qb + t * 512);
#pragma unroll
    for (int t = 0; t < 6; ++t) KEEP(bfr[t]);
  }
  const float dq = db[q0 + lo];
  float slse = 0.f, sdep = 0.f;

  const int t0 = h * 64 + w * 8;
  const unsigned short* ab = Cb + ((size_t)t0 * 6) * 512 + lane * 8;

  bf16x8 a0[6], a1[6];
#pragma unroll
  for (int t = 0; t < 6; ++t) a0[t] = *(const bf16x8*)(ab + t * 512);
#pragma unroll
  for (int t = 0; t < 6; ++t) KEEP(a0[t]);

#define PROC3(A, GT)                                                           \
  {                                                                            \
    f32x16 acc = zero16();                                                     \
    _Pragma("unroll")                                                          \
    for (int t = 0; t < 6; ++t)                                                \
      acc = __builtin_amdgcn_mfma_f32_32x32x16_bf16(A[t], bfr[t], acc, 0, 0, 0); \
    float dvv[16];                                                             \
    _Pragma("unroll")                                                          \
    for (int k = 0; k < 4; ++k) {                                              \
      float4 dv = *(const float4*)(db + (GT) * 32 + hi4 + 8 * k);              \
      dvv[k * 4 + 0] = dv.x; dvv[k * 4 + 1] = dv.y;                            \
      dvv[k * 4 + 2] = dv.z; dvv[k * 4 + 3] = dv.w;                            \
    }                                                                          \
    _Pragma("unroll")                                                          \
    for (int r = 0; r < 16; ++r) {                                             \
      const float s = acc[r];                                                  \
      const float dd = dq - dvv[r];                                            \
      sdep += __expf(-2.f * dd * dd) * (1.f - s);                              \
      slse += __expf(fmaf(s, 10.f, -10.f));                                    \
    }                                                                          \
  }

  for (int mt = 0; mt < 8; mt += 2) {
    {
      const unsigned short* ar = ab + (size_t)(mt + 1) * 6 * 512;
#pragma unroll
      for (int t = 0; t < 6; ++t) a1[t] = *(const bf16x8*)(ar + t * 512);
#pragma unroll
      for (int t = 0; t < 6; ++t) KEEP(a1[t]);
    }
    PROC3(a0, t0 + mt)
    if (mt + 2 < 8) {
      const unsigned short* ar = ab + (size_t)(mt + 2) * 6 * 512;
#pragma unroll
      for (int t = 0; t < 6; ++t) a0[t] = *(const bf16x8*)(ar + t * 512);
#pragma unroll
      for (int t = 0; t < 6; ++t) KEEP(a0[t]);
    }
    PROC3(a1, t0 + mt + 1)
  }
#undef PROC3

  slse += __shfl_xor(slse, 32, 64);
  if (lane < 32) lsep[w][lo] = slse;
#pragma unroll
  for (int m = 1; m <= 32; m <<= 1) sdep += __shfl_xor(sdep, m, 64);
  if (lane == 0) depp[w] = sdep;
  __syncthreads();
  if (tid < 32) {
    float tot = 0.f;
#pragma unroll
    for (int w2 = 0; w2 < 8; ++w2) tot += lsep[w2][tid];
    slse_part[(size_t)((h * 2 + b) * NPTS) + q0 + tid] = tot;   // raw exp-sum
  }
  if (tid == 32) {
    float d = 0.f;
#pragma unroll
    for (int w2 = 0; w2 < 8; ++w2) d += depp[w2];
    dpart[g] = d;
  }
}

// ---------------------------------------------------------------------------
// K4: merge the four quarter-candidate lists, force self, then 7 positive-pair
// code dots in FP32 from raw codes. One wave per row.
// ---------------------------------------------------------------------------
__global__ __launch_bounds__(64) void gather_pos(const float* __restrict__ codes,
                                                 const float* __restrict__ invc,
                                                 const unsigned* __restrict__ cand,
                                                 float* __restrict__ gpart) {
  const int n = blockIdx.x;              // 0..8191 (global row)
  const int b = n >> 12, q = n & 4095;
  const int lane = threadIdx.x;

  unsigned s[7];
#pragma unroll
  for (int t = 0; t < 7; ++t) s[t] = KSENT;
#pragma unroll
  for (int pp = 0; pp < 4; ++pp) {
    const unsigned* cp = cand + ((size_t)((pp * 2 + b) * NPTS) + q) * 7;
#pragma unroll
    for (int t = 0; t < 7; ++t) cas7(cp[t], s);
  }
  // FORCE self (self-sim is always the reference max)
  bool has = false;
#pragma unroll
  for (int t = 0; t < 7; ++t) has = has || ((s[t] & 4095u) == (unsigned)q);
  if (!has) s[6] = (unsigned)q;

  const float* cn = codes + (size_t)n * 90;
  float2 a = make_float2(0.f, 0.f);
  if (lane < 45) a = *(const float2*)(cn + lane * 2);
  const float inva = invc[n];
  float ssum = 0.f;
#pragma unroll
  for (int k = 0; k < 7; ++k) {
    const int m = (int)(s[k] & 4095u);
    const float* cm = codes + ((size_t)(b << 12) + m) * 90;
    float2 bb = make_float2(0.f, 0.f);
    if (lane < 45) bb = *(const float2*)(cm + lane * 2);
    float p = fmaf(a.x, bb.x, a.y * bb.y);
#pragma unroll
    for (int w = 1; w <= 32; w <<= 1) p += __shfl_xor(p, w, 64);
    ssum += p * inva * invc[(b << 12) + m];
  }
  if (lane == 0) gpart[n] = ssum;
}

// ---------------------------------------------------------------------------
// K5: finalize -> (l_stego, l_depthg, total). Log of merged 2-half exp-sums.
// ---------------------------------------------------------------------------
__global__ __launch_bounds__(256) void finalize(const float* __restrict__ slse_part,
                                                const float* __restrict__ gpart,
                                                const float* __restrict__ dpart,
                                                float* __restrict__ out) {
  const int tid = threadIdx.x;
  float s1 = 0.f, s2 = 0.f;
  for (int n = tid; n < 2 * NPTS; n += 256) {
    const int b = n >> 12, q = n & 4095;
    const float pz = slse_part[b * NPTS + q] + slse_part[(2 + b) * NPTS + q];
    s1 += 10.f + __logf(pz);
    s2 += gpart[n];
  }
  float s3 = dpart[tid] + dpart[tid + 256];
  __shared__ float r1[256], r2[256], r3[256];
  r1[tid] = s1; r2[tid] = s2; r3[tid] = s3;
  __syncthreads();
  for (int s = 128; s > 0; s >>= 1) {
    if (tid < s) { r1[tid] += r1[tid + s]; r2[tid] += r2[tid + s]; r3[tid] += r3[tid + s]; }
    __syncthreads();
  }
  if (tid == 0) {
    const float l_st = (7.f * r1[0] - 10.f * r2[0]) / 57344.f;
    const float l_dp = r3[0] / 33554432.f;
    out[0] = l_st;
    out[1] = l_dp;
    out[2] = l_st + 0.3f * l_dp;
  }
}

// ---------------------------------------------------------------------------
// ws layout (peak ~4.1 MB <= proven-safe 8.19 MB):
//   invc      @ 0        (32768)    [norm_c .. gather]
//   cand      @ 32768    (917504)   [knn .. gather]
//   Fsw8      @ 950272   (3145728)  [norm_f .. knn]  -- dead after knn:
//     Csw       @ 950272  (1572864)  [norm_c .. lse]  (overlays dead Fsw8)
//     slse_part @ 2523136 (65536)    [lse .. finalize]
//     dpart     @ 2654208 (2048)
//     gpart     @ 2658304 (32768)
// ---------------------------------------------------------------------------
extern "C" void kernel_launch(void* const* d_in, const int* in_sizes, int n_in,
                              void* d_out, int out_size, void* d_ws, size_t ws_size,
                              hipStream_t stream) {
  (void)in_sizes; (void)n_in; (void)out_size; (void)ws_size;
  const float* codes = (const float*)d_in[0];   // (B,N,90)
  const float* feats = (const float*)d_in[1];   // (B,N,384)
  const float* depth = (const float*)d_in[2];   // (B,N)
  float* out = (float*)d_out;

  char* ws = (char*)d_ws;
  float*    invc      = (float*)ws;
  unsigned* cand      = (unsigned*)(ws + 32768);
  unsigned char*  Fsw8 = (unsigned char*)(ws + 950272);
  unsigned short* Csw  = (unsigned short*)(ws + 950272);
  float*    slse_part = (float*)(ws + 2523136);
  float*    dpart     = (float*)(ws + 2654208);
  float*    gpart     = (float*)(ws + 2658304);

  norm_f<<<2 * NPTS, 64, 0, stream>>>(feats, Fsw8);
  knn_mfma<<<1024, 256, 0, stream>>>(Fsw8, cand);
  norm_c<<<2 * NPTS, 64, 0, stream>>>(codes, Csw, invc);   // Csw overlays dead Fsw8
  lse_depth<<<512, 512, 0, stream>>>(Csw, depth, slse_part, dpart);
  gather_pos<<<2 * NPTS, 64, 0, stream>>>(codes, invc, cand, gpart);
  finalize<<<1, 256, 0, stream>>>(slse_part, gpart, dpart, out);
}